// Round 1
// baseline (218.277 us; speedup 1.0000x reference)
//
#include <hip/hip_runtime.h>

// EMA along T for [B=8, C=64, F=128, T=2000] fp32.
// One 64-lane wave per (b,c,f) row; wave-parallel linear-recurrence scan
// along T in chunks of 256 elements (4 per lane), fully coalesced loads/stores.

#define T_LEN 2000
#define NROWS 65536   // 8*64*128
#define F_DIM 128
#define C_DIM 64

__global__ __launch_bounds__(256) void ema_scan_kernel(
    const float* __restrict__ x,       // [NROWS][T_LEN]
    const float* __restrict__ init,    // [NROWS]
    const float* __restrict__ weights, // [C_DIM]
    float* __restrict__ out,           // [NROWS][T_LEN]
    float* __restrict__ final_out)     // [NROWS]
{
    const int gwave = (blockIdx.x * blockDim.x + threadIdx.x) >> 6;
    const int lane  = threadIdx.x & 63;
    if (gwave >= NROWS) return;
    const int row = gwave;
    const int c   = (row >> 7) & (C_DIM - 1);   // row = ((b*C)+c)*F + f

    float w = weights[c];
    w = fminf(fmaxf(w, 0.0f), 1.0f);
    const float a = 1.0f - w;

    // Powers of a via repeated squaring.
    const float a2   = a * a;
    const float a3   = a2 * a;
    const float a4   = a2 * a2;
    const float a8   = a4 * a4;
    const float a16  = a8 * a8;
    const float a32  = a16 * a16;
    const float a64  = a32 * a32;
    const float a128 = a64 * a64;
    const float a256 = a128 * a128;

    // a^(4*lane) from lane bits (constant across chunks).
    float pw = 1.0f;
    if (lane & 1)  pw *= a4;
    if (lane & 2)  pw *= a8;
    if (lane & 4)  pw *= a16;
    if (lane & 8)  pw *= a32;
    if (lane & 16) pw *= a64;
    if (lane & 32) pw *= a128;

    float acc = init[row];   // running state at chunk boundaries (wave-uniform)

    const float* __restrict__ xrow = x   + (long long)row * T_LEN;
    float* __restrict__       orow = out + (long long)row * T_LEN;

    #pragma unroll 1
    for (int t0 = 0; t0 < T_LEN; t0 += 256) {
        const int tl  = t0 + lane * 4;   // this lane's first element
        const int rem = T_LEN - tl;      // elements available at tl (may be <=0)

        float x0 = 0.0f, x1 = 0.0f, x2 = 0.0f, x3 = 0.0f;
        if (rem >= 4) {
            const float4 v = *reinterpret_cast<const float4*>(xrow + tl);
            x0 = v.x; x1 = v.y; x2 = v.z; x3 = v.w;
        } else if (rem > 0) {
            x0 = xrow[tl];
            if (rem > 1) x1 = xrow[tl + 1];
            if (rem > 2) x2 = xrow[tl + 2];
        }

        // Local 4-element segment reduce: B = w*(a^3 x0 + a^2 x1 + a x2 + x3)
        float B = w * fmaf(a3, x0, fmaf(a2, x1, fmaf(a, x2, x3)));

        // Kogge-Stone inclusive scan over 64 lanes.
        // At offset d, current partial covers exactly d lane-segments (4d elems)
        // for every updating lane, so the combine is B = a^(4d)*B_up + B.
        float Bup;
        Bup = __shfl_up(B, 1);  if (lane >= 1)  B = fmaf(a4,   Bup, B);
        Bup = __shfl_up(B, 2);  if (lane >= 2)  B = fmaf(a8,   Bup, B);
        Bup = __shfl_up(B, 4);  if (lane >= 4)  B = fmaf(a16,  Bup, B);
        Bup = __shfl_up(B, 8);  if (lane >= 8)  B = fmaf(a32,  Bup, B);
        Bup = __shfl_up(B, 16); if (lane >= 16) B = fmaf(a64,  Bup, B);
        Bup = __shfl_up(B, 32); if (lane >= 32) B = fmaf(a128, Bup, B);

        // Exclusive prefix for this lane (covers chunk elements [0, 4*lane)).
        float Bexcl = __shfl_up(B, 1);
        if (lane == 0) Bexcl = 0.0f;

        // State entering this lane's segment.
        float accl = fmaf(pw, acc, Bexcl);

        // Serial epilogue: reconstruct per-element outputs.
        if (rem >= 4) {
            float4 o;
            accl = fmaf(a, accl, w * x0); o.x = accl;
            accl = fmaf(a, accl, w * x1); o.y = accl;
            accl = fmaf(a, accl, w * x2); o.z = accl;
            accl = fmaf(a, accl, w * x3); o.w = accl;
            *reinterpret_cast<float4*>(orow + tl) = o;
            if (tl + 4 == T_LEN) final_out[row] = accl;
        } else if (rem > 0) {
            accl = fmaf(a, accl, w * x0); orow[tl] = accl;
            if (rem > 1) { accl = fmaf(a, accl, w * x1); orow[tl + 1] = accl; }
            if (rem > 2) { accl = fmaf(a, accl, w * x2); orow[tl + 2] = accl; }
            final_out[row] = accl;   // tl + rem == T_LEN by construction
        }

        // Carry to next chunk (wave-uniform; garbage-but-unused on last chunk).
        const float Btop = __shfl(B, 63);
        acc = fmaf(a256, acc, Btop);
    }
}

extern "C" void kernel_launch(void* const* d_in, const int* in_sizes, int n_in,
                              void* d_out, int out_size, void* d_ws, size_t ws_size,
                              hipStream_t stream) {
    const float* mag  = (const float*)d_in[0];   // [8,64,128,2000]
    const float* init = (const float*)d_in[1];   // [8,64,128,1]
    const float* wgt  = (const float*)d_in[2];   // [64]
    float* out = (float*)d_out;                  // [8,64,128,2000] then [8,64,128,1]
    float* fin = out + (long long)NROWS * T_LEN;

    const int threads = 256;                 // 4 waves/block -> 4 rows/block
    const int blocks  = NROWS / 4;           // 16384
    ema_scan_kernel<<<blocks, threads, 0, stream>>>(mag, init, wgt, out, fin);
}

// Round 2
// 180.422 us; speedup vs baseline: 1.2098x; 1.2098x over previous
//
#include <hip/hip_runtime.h>

// EMA along T for [B=8, C=64, F=128, T=2000] fp32.
// One 64-lane wave per (b,c,f) row. T is covered by 8 chunks of 256 elems
// (last chunk is 208 = 52 lanes x 4 -- every active lane always loads a FULL
// float4). All 8 chunk loads are hoisted up-front (8 KB in flight per wave),
// then 8 wave-level Kogge-Stone linear-recurrence scans run as pure VALU work.

typedef float f32x4 __attribute__((ext_vector_type(4)));

#define T_LEN 2000
#define NROWS 65536   // 8*64*128
#define C_DIM 64
#define NCHUNK 8
#define TAIL_LANES 52 // (2000 - 7*256)/4

__global__ __launch_bounds__(256) void ema_scan_kernel(
    const float* __restrict__ x,       // [NROWS][T_LEN]
    const float* __restrict__ init,    // [NROWS]
    const float* __restrict__ weights, // [C_DIM]
    float* __restrict__ out,           // [NROWS][T_LEN]
    float* __restrict__ final_out)     // [NROWS]
{
    const int gwave = (blockIdx.x * blockDim.x + threadIdx.x) >> 6;
    const int lane  = threadIdx.x & 63;
    if (gwave >= NROWS) return;
    const int row = gwave;
    const int c   = (row >> 7) & (C_DIM - 1);   // row = ((b*C)+c)*F + f

    float w = weights[c];
    w = fminf(fmaxf(w, 0.0f), 1.0f);
    const float a = 1.0f - w;

    // Powers of a via repeated squaring.
    const float a2   = a * a;
    const float a3   = a2 * a;
    const float a4   = a2 * a2;
    const float a8   = a4 * a4;
    const float a16  = a8 * a8;
    const float a32  = a16 * a16;
    const float a64  = a32 * a32;
    const float a128 = a64 * a64;
    const float a256 = a128 * a128;

    // a^(4*lane) from lane bits (constant across chunks).
    float pw = 1.0f;
    if (lane & 1)  pw *= a4;
    if (lane & 2)  pw *= a8;
    if (lane & 4)  pw *= a16;
    if (lane & 8)  pw *= a32;
    if (lane & 16) pw *= a64;
    if (lane & 32) pw *= a128;

    const float* __restrict__ xrow = x   + (long long)row * T_LEN;
    float* __restrict__       orow = out + (long long)row * T_LEN;
    const int tl = lane * 4;

    // ---- Hoist ALL chunk loads: 8 outstanding 1KB wave-loads (streamed, nt).
    f32x4 v[NCHUNK];
    #pragma unroll
    for (int i = 0; i < NCHUNK - 1; ++i)
        v[i] = __builtin_nontemporal_load(
                   reinterpret_cast<const f32x4*>(xrow + i * 256 + tl));
    if (lane < TAIL_LANES)
        v[NCHUNK - 1] = __builtin_nontemporal_load(
                   reinterpret_cast<const f32x4*>(xrow + (NCHUNK - 1) * 256 + tl));
    else {
        f32x4 z = {0.0f, 0.0f, 0.0f, 0.0f};
        v[NCHUNK - 1] = z;
    }

    float acc = init[row];   // running state at chunk boundaries (wave-uniform)

    #pragma unroll
    for (int i = 0; i < NCHUNK; ++i) {
        const f32x4 xv = v[i];

        // Local 4-elem segment reduce: B = w*(a^3 x0 + a^2 x1 + a x2 + x3)
        float B = w * fmaf(a3, xv.x, fmaf(a2, xv.y, fmaf(a, xv.z, xv.w)));

        // Kogge-Stone inclusive scan over 64 lanes; combine B = a^(4d)*B_up + B.
        float Bup;
        Bup = __shfl_up(B, 1);  if (lane >= 1)  B = fmaf(a4,   Bup, B);
        Bup = __shfl_up(B, 2);  if (lane >= 2)  B = fmaf(a8,   Bup, B);
        Bup = __shfl_up(B, 4);  if (lane >= 4)  B = fmaf(a16,  Bup, B);
        Bup = __shfl_up(B, 8);  if (lane >= 8)  B = fmaf(a32,  Bup, B);
        Bup = __shfl_up(B, 16); if (lane >= 16) B = fmaf(a64,  Bup, B);
        Bup = __shfl_up(B, 32); if (lane >= 32) B = fmaf(a128, Bup, B);

        // Exclusive prefix for this lane.
        float Bexcl = __shfl_up(B, 1);
        if (lane == 0) Bexcl = 0.0f;

        // State entering this lane's 4-elem segment.
        float accl = fmaf(pw, acc, Bexcl);

        // Serial epilogue: per-element outputs.
        f32x4 o;
        accl = fmaf(a, accl, w * xv.x); o.x = accl;
        accl = fmaf(a, accl, w * xv.y); o.y = accl;
        accl = fmaf(a, accl, w * xv.z); o.z = accl;
        accl = fmaf(a, accl, w * xv.w); o.w = accl;

        if (i < NCHUNK - 1) {
            __builtin_nontemporal_store(o,
                reinterpret_cast<f32x4*>(orow + i * 256 + tl));
            // Carry to next chunk (wave-uniform).
            const float Btop = __shfl(B, 63);
            acc = fmaf(a256, acc, Btop);
        } else if (lane < TAIL_LANES) {
            __builtin_nontemporal_store(o,
                reinterpret_cast<f32x4*>(orow + (NCHUNK - 1) * 256 + tl));
            if (lane == TAIL_LANES - 1) final_out[row] = accl;
        }
    }
}

extern "C" void kernel_launch(void* const* d_in, const int* in_sizes, int n_in,
                              void* d_out, int out_size, void* d_ws, size_t ws_size,
                              hipStream_t stream) {
    const float* mag  = (const float*)d_in[0];   // [8,64,128,2000]
    const float* init = (const float*)d_in[1];   // [8,64,128,1]
    const float* wgt  = (const float*)d_in[2];   // [64]
    float* out = (float*)d_out;                  // [8,64,128,2000] then [8,64,128,1]
    float* fin = out + (long long)NROWS * T_LEN;

    const int threads = 256;                 // 4 waves/block -> 4 rows/block
    const int blocks  = NROWS / 4;           // 16384
    ema_scan_kernel<<<blocks, threads, 0, stream>>>(mag, init, wgt, out, fin);
}